// Round 17
// baseline (69.082 us; speedup 1.0000x reference)
//
#include <hip/hip_runtime.h>
#include <hip/hip_bf16.h>
#include <math.h>

typedef short short8 __attribute__((ext_vector_type(8)));
typedef float f32x4  __attribute__((ext_vector_type(4)));

#define C_CURV 0.01f
#define SQRT_C 0.1f
#define EPSF   1e-15f
#define MAX_TANH 0.99999f   // 1 - 1e-5

__device__ __forceinline__ unsigned short f32_to_bf16(float x) {
    unsigned u = __builtin_bit_cast(unsigned, x);
    u += 0x7FFFu + ((u >> 16) & 1u);          // RNE
    return (unsigned short)(u >> 16);
}

__device__ __forceinline__ float wave_reduce_sum(float v) {
    #pragma unroll
    for (int off = 32; off > 0; off >>= 1)
        v += __shfl_xor(v, off, 64);
    return v;
}

// One 64-thread wave per triplet. Lane owns dims d and d+64.
__global__ __launch_bounds__(64)
void build_queries(const float* __restrict__ ent,
                   const int*   __restrict__ trip,
                   const float* __restrict__ rel_diag,
                   const float* __restrict__ rel_trans,
                   const float* __restrict__ ent_bias,
                   unsigned short* __restrict__ qh,   // [B][128] bf16
                   float* __restrict__ q2_out,        // [B]
                   float* __restrict__ bs_out)        // [B]
{
    const int b = blockIdx.x;
    const int d = threadIdx.x;
    const int s = trip[3 * b + 0];
    const int r = trip[3 * b + 1];

    const float* srow = ent + (size_t)s * 128;
    float x0 = srow[d], x1 = srow[d + 64];

    float n1 = fmaxf(sqrtf(wave_reduce_sum(x0 * x0 + x1 * x1)), EPSF);
    float a1 = atanhf(fminf(SQRT_C * n1, MAX_TANH)) / (SQRT_C * n1);
    float u0 = a1 * x0, u1 = a1 * x1;

    const float* rrow = rel_diag + (size_t)r * 128;
    float v0 = rrow[d] * u0, v1 = rrow[d + 64] * u1;
    float n2 = fmaxf(sqrtf(wave_reduce_sum(v0 * v0 + v1 * v1)), EPSF);
    float s2 = tanhf(SQRT_C * n2) / (SQRT_C * n2);
    float rs0 = s2 * v0, rs1 = s2 * v1;

    const float* trow = rel_trans + (size_t)r * 128;
    float t0 = trow[d], t1 = trow[d + 64];
    float n3 = fmaxf(sqrtf(wave_reduce_sum(t0 * t0 + t1 * t1)), EPSF);
    float s3 = tanhf(SQRT_C * n3) / (SQRT_C * n3);
    float tr0 = s3 * t0, tr1 = s3 * t1;

    float x2 = wave_reduce_sum(rs0 * rs0 + rs1 * rs1);
    float y2 = wave_reduce_sum(tr0 * tr0 + tr1 * tr1);
    float xy = wave_reduce_sum(rs0 * tr0 + rs1 * tr1);
    float cA = 1.f + 2.f * C_CURV * xy + C_CURV * y2;
    float cB = 1.f - C_CURV * x2;
    float den = 1.f + 2.f * C_CURV * xy + C_CURV * C_CURV * x2 * y2;
    den = fmaxf(den, EPSF);
    float inv = 1.f / den;
    float q0 = (cA * rs0 + cB * tr0) * inv;
    float q1 = (cA * rs1 + cB * tr1) * inv;

    float q2 = wave_reduce_sum(q0 * q0 + q1 * q1);

    qh[(size_t)b * 128 + d]      = f32_to_bf16(q0);
    qh[(size_t)b * 128 + d + 64] = f32_to_bf16(q1);
    if (d == 0) { q2_out[b] = q2; bs_out[b] = ent_bias[s]; }
}

// One 64-entity tile per block. Tile bf16 in XOR-swizzled LDS; per-wave chunk
// = 16 q-rows x 64 e. Single bf16 MFMA pass, Mobius-norm epilogue, scalar
// stores rows-outer (R10/R14/R15-validated). R17: A-fragment double-buffer —
// chunk 0 loads issued BEFORE the staging barrier (hide under conversion),
// chunk bm+1 loads issued before the epilogue (hide under epilogue+stores).
// +16 VGPR -> launch_bounds(256,3) (budget 256/3=84; kernel ~80, no spill).
__global__ __launch_bounds__(256, 3)
void gemm_score(const float* __restrict__ ent,
                const float* __restrict__ ent_bias,
                const unsigned short* __restrict__ qh,
                const float* __restrict__ q2a,
                const float* __restrict__ bsa,
                float* __restrict__ out,
                int E, int B)
{
    __shared__ char  EH[64 * 256];   // 16 KB: entity tile bf16, XOR-swizzled
    __shared__ float E2L[64], EBL[64];
    __shared__ float Q2S[1024], BSS[1024];   // B<=1024 fast path

    const int t = threadIdx.x;
    const int lane = t & 63, wid = t >> 6;     // 4 waves, each 16 q-rows x 64 e
    const int l15 = lane & 15, lk = lane >> 4;
    const int r_ = t >> 2, h_ = t & 3;         // staging: 4 threads per row
    const int swzr = (r_ & 7) << 4;
    const int rswz = (l15 & 7) << 4;
    const float c = C_CURV;
    const int nbm = (B + 63) >> 6;
    const int tile = blockIdx.x;
    const int tb = tile * 64;
    const bool lds_qb = (B <= 1024);

    // A-frag base for this lane (row index within a chunk is fixed: wid*16+l15)
    const int arow0 = wid * 16 + l15;

    // ---- prefetch chunk 0 A-fragments (independent of LDS staging) ----
    short8 AH[4];
    {
        int ar = arow0; if (ar > B - 1) ar = B - 1;
        const char* ph = (const char*)qh + (size_t)ar * 256 + lk * 16;
        #pragma unroll
        for (int kk = 0; kk < 4; ++kk)
            AH[kk] = *(const short8*)(ph + kk * 64);
    }

    {   // ---- stage + convert entity tile -> LDS (+ e2 via shuffles) ----
        int g = tb + r_; if (g > E - 1) g = E - 1;
        const float4* src = (const float4*)(ent + (size_t)g * 128 + h_ * 32);
        float ss = 0.f;
        #pragma unroll
        for (int j = 0; j < 4; ++j) {
            float4 v0 = src[2 * j], v1 = src[2 * j + 1];
            short8 hi8;
            hi8[0] = (short)f32_to_bf16(v0.x); ss = fmaf(v0.x, v0.x, ss);
            hi8[1] = (short)f32_to_bf16(v0.y); ss = fmaf(v0.y, v0.y, ss);
            hi8[2] = (short)f32_to_bf16(v0.z); ss = fmaf(v0.z, v0.z, ss);
            hi8[3] = (short)f32_to_bf16(v0.w); ss = fmaf(v0.w, v0.w, ss);
            hi8[4] = (short)f32_to_bf16(v1.x); ss = fmaf(v1.x, v1.x, ss);
            hi8[5] = (short)f32_to_bf16(v1.y); ss = fmaf(v1.y, v1.y, ss);
            hi8[6] = (short)f32_to_bf16(v1.z); ss = fmaf(v1.z, v1.z, ss);
            hi8[7] = (short)f32_to_bf16(v1.w); ss = fmaf(v1.w, v1.w, ss);
            *(short8*)(EH + r_ * 256 + ((h_ * 64 + j * 16) ^ swzr)) = hi8;
        }
        ss += __shfl_xor(ss, 1, 64);
        ss += __shfl_xor(ss, 2, 64);
        if (h_ == 0) E2L[r_] = ss;
        if (t < 64) { int gc = tb + t; if (gc > E - 1) gc = E - 1; EBL[t] = ent_bias[gc]; }
        if (lds_qb) {
            for (int i = t; i < B; i += 256) { Q2S[i] = q2a[i]; BSS[i] = bsa[i]; }
        }
    }
    __syncthreads();

    // column validity (per n), cheap per-block
    bool cvr[4];
    #pragma unroll
    for (int n = 0; n < 4; ++n) cvr[n] = (tb + n * 16 + l15 < E);

    #pragma unroll 1
    for (int bm = 0; bm < nbm; ++bm) {
        const int bmb = bm << 6;

        // per-row scalars (rows lk*4+r) from LDS
        float q2r[4], bsr[4];
        #pragma unroll
        for (int r = 0; r < 4; ++r) {
            int row = bmb + wid * 16 + lk * 4 + r;
            int rc = row < B ? row : (B - 1);
            q2r[r] = lds_qb ? Q2S[rc] : q2a[rc];
            bsr[r] = lds_qb ? BSS[rc] : bsa[rc];
        }

        f32x4 acc[4];
        #pragma unroll
        for (int n = 0; n < 4; ++n) acc[n] = (f32x4){0.f, 0.f, 0.f, 0.f};

        __builtin_amdgcn_s_setprio(1);
        #pragma unroll
        for (int kk = 0; kk < 4; ++kk) {
            const int ko = (kk * 64 + lk * 16) ^ rswz;
            #pragma unroll
            for (int n = 0; n < 4; ++n) {
                short8 BH = *(const short8*)(EH + (n * 16 + l15) * 256 + ko);
                acc[n] = __builtin_amdgcn_mfma_f32_16x16x32_bf16(AH[kk], BH, acc[n], 0, 0, 0);
            }
        }
        __builtin_amdgcn_s_setprio(0);

        // ---- prefetch next chunk's A-fragments (hide under epilogue) ----
        if (bm + 1 < nbm) {
            int ar = (bmb + 64) + arow0; if (ar > B - 1) ar = B - 1;
            const char* ph = (const char*)qh + (size_t)ar * 256 + lk * 16;
            #pragma unroll
            for (int kk = 0; kk < 4; ++kk)
                AH[kk] = *(const short8*)(ph + kk * 64);
        }

        // per-n constants from LDS
        float e2q[4], beq[4];
        #pragma unroll
        for (int n = 0; n < 4; ++n) {
            e2q[n] = E2L[n * 16 + l15];
            beq[n] = EBL[n * 16 + l15];
        }

        // fused epilogue (Mobius-norm identity), rows outer / cols inner
        #pragma unroll
        for (int r = 0; r < 4; ++r) {
            const int row = bmb + wid * 16 + lk * 4 + r;
            const float q2 = q2r[r];
            const float c2q2 = c * c * q2;
            const unsigned base = (unsigned)row * (unsigned)E;
            const bool rv = (row < B);
            #pragma unroll
            for (int n = 0; n < 4; ++n) {
                const float d  = acc[n][r];
                const float e2 = e2q[n];
                float den  = fmaf(-2.f * c, d, fmaf(c2q2, e2, 1.f));
                float num  = fmaf(-2.f, d, q2 + e2);
                float inv  = __builtin_amdgcn_rcpf(den);
                float sc   = fmaf(-num, inv, beq[n] + bsr[r]);
                if (rv && cvr[n])
                    out[base + (unsigned)(tb + n * 16 + l15)] = sc;
            }
        }
    }
}

extern "C" void kernel_launch(void* const* d_in, const int* in_sizes, int n_in,
                              void* d_out, int out_size, void* d_ws, size_t ws_size,
                              hipStream_t stream) {
    const float* ent       = (const float*)d_in[0];
    // d_in[1] = rel_embedding (unused)
    const int*   trip      = (const int*)d_in[2];
    const float* rel_diag  = (const float*)d_in[3];
    const float* rel_trans = (const float*)d_in[4];
    const float* ent_bias  = (const float*)d_in[5];

    const int D = 128;
    const int E = in_sizes[0] / D;
    const int B = in_sizes[2] / 3;

    unsigned char* ws = (unsigned char*)d_ws;
    unsigned short* qh = (unsigned short*)ws;               // B*128 bf16
    float* q2w = (float*)(ws + 131072);                     // B
    float* bsw = (float*)(ws + 131072 + 2048);              // B

    build_queries<<<B, 64, 0, stream>>>(ent, trip, rel_diag, rel_trans, ent_bias,
                                        qh, q2w, bsw);

    const int ntiles = (E + 63) / 64;
    gemm_score<<<ntiles, 256, 0, stream>>>(ent, ent_bias, qh, q2w, bsw,
                                           (float*)d_out, E, B);
}

// Round 18
// 62.903 us; speedup vs baseline: 1.0982x; 1.0982x over previous
//
#include <hip/hip_runtime.h>
#include <hip/hip_bf16.h>
#include <math.h>

typedef short short8 __attribute__((ext_vector_type(8)));
typedef float f32x4  __attribute__((ext_vector_type(4)));

#define C_CURV 0.01f
#define SQRT_C 0.1f
#define EPSF   1e-15f
#define MAX_TANH 0.99999f   // 1 - 1e-5

__device__ __forceinline__ unsigned short f32_to_bf16(float x) {
    unsigned u = __builtin_bit_cast(unsigned, x);
    u += 0x7FFFu + ((u >> 16) & 1u);          // RNE
    return (unsigned short)(u >> 16);
}

__device__ __forceinline__ float wave_reduce_sum(float v) {
    #pragma unroll
    for (int off = 32; off > 0; off >>= 1)
        v += __shfl_xor(v, off, 64);
    return v;
}

// One 64-thread wave per triplet. Lane owns dims d and d+64.
__global__ __launch_bounds__(64)
void build_queries(const float* __restrict__ ent,
                   const int*   __restrict__ trip,
                   const float* __restrict__ rel_diag,
                   const float* __restrict__ rel_trans,
                   const float* __restrict__ ent_bias,
                   unsigned short* __restrict__ qh,   // [B][128] bf16
                   float* __restrict__ q2_out,        // [B]
                   float* __restrict__ bs_out)        // [B]
{
    const int b = blockIdx.x;
    const int d = threadIdx.x;
    const int s = trip[3 * b + 0];
    const int r = trip[3 * b + 1];

    const float* srow = ent + (size_t)s * 128;
    float x0 = srow[d], x1 = srow[d + 64];

    float n1 = fmaxf(sqrtf(wave_reduce_sum(x0 * x0 + x1 * x1)), EPSF);
    float a1 = atanhf(fminf(SQRT_C * n1, MAX_TANH)) / (SQRT_C * n1);
    float u0 = a1 * x0, u1 = a1 * x1;

    const float* rrow = rel_diag + (size_t)r * 128;
    float v0 = rrow[d] * u0, v1 = rrow[d + 64] * u1;
    float n2 = fmaxf(sqrtf(wave_reduce_sum(v0 * v0 + v1 * v1)), EPSF);
    float s2 = tanhf(SQRT_C * n2) / (SQRT_C * n2);
    float rs0 = s2 * v0, rs1 = s2 * v1;

    const float* trow = rel_trans + (size_t)r * 128;
    float t0 = trow[d], t1 = trow[d + 64];
    float n3 = fmaxf(sqrtf(wave_reduce_sum(t0 * t0 + t1 * t1)), EPSF);
    float s3 = tanhf(SQRT_C * n3) / (SQRT_C * n3);
    float tr0 = s3 * t0, tr1 = s3 * t1;

    float x2 = wave_reduce_sum(rs0 * rs0 + rs1 * rs1);
    float y2 = wave_reduce_sum(tr0 * tr0 + tr1 * tr1);
    float xy = wave_reduce_sum(rs0 * tr0 + rs1 * tr1);
    float cA = 1.f + 2.f * C_CURV * xy + C_CURV * y2;
    float cB = 1.f - C_CURV * x2;
    float den = 1.f + 2.f * C_CURV * xy + C_CURV * C_CURV * x2 * y2;
    den = fmaxf(den, EPSF);
    float inv = 1.f / den;
    float q0 = (cA * rs0 + cB * tr0) * inv;
    float q1 = (cA * rs1 + cB * tr1) * inv;

    float q2 = wave_reduce_sum(q0 * q0 + q1 * q1);

    qh[(size_t)b * 128 + d]      = f32_to_bf16(q0);
    qh[(size_t)b * 128 + d + 64] = f32_to_bf16(q1);
    if (d == 0) { q2_out[b] = q2; bs_out[b] = ent_bias[s]; }
}

// One 64-entity tile per block (grid = ceil(E/64)). Tile bf16 in XOR-swizzled
// LDS; per-wave chunk = 16 q-rows x 64 e (R13 shape, 64-VGPR budget of
// (256,4), 16 waves/CU). Single bf16 MFMA pass. R14 Mobius-norm epilogue.
// Scalar stores, rows outer / cols inner (R15 PROVED float4 16-row-scatter
// stores are worse; R10 proved NT worse). R16: s_setprio around MFMA (waves
// run independently after staging barrier -> attn-like regime where T5 wins)
// + q2/bs staged in LDS once per block (off the per-chunk L2 path).
__global__ __launch_bounds__(256, 4)
void gemm_score(const float* __restrict__ ent,
                const float* __restrict__ ent_bias,
                const unsigned short* __restrict__ qh,
                const float* __restrict__ q2a,
                const float* __restrict__ bsa,
                float* __restrict__ out,
                int E, int B)
{
    __shared__ char  EH[64 * 256];   // 16 KB: entity tile bf16, XOR-swizzled
    __shared__ float E2L[64], EBL[64];
    __shared__ float Q2S[1024], BSS[1024];   // B<=1024 fast path

    const int t = threadIdx.x;
    const int lane = t & 63, wid = t >> 6;     // 4 waves, each 16 q-rows x 64 e
    const int l15 = lane & 15, lk = lane >> 4;
    const int r_ = t >> 2, h_ = t & 3;         // staging: 4 threads per row
    const int swzr = (r_ & 7) << 4;
    const int rswz = (l15 & 7) << 4;
    const float c = C_CURV;
    const int nbm = (B + 63) >> 6;
    const int tile = blockIdx.x;
    const int tb = tile * 64;
    const bool lds_qb = (B <= 1024);

    {   // ---- stage + convert entity tile -> LDS (+ e2 via shuffles) ----
        int g = tb + r_; if (g > E - 1) g = E - 1;
        const float4* src = (const float4*)(ent + (size_t)g * 128 + h_ * 32);
        float ss = 0.f;
        #pragma unroll
        for (int j = 0; j < 4; ++j) {
            float4 v0 = src[2 * j], v1 = src[2 * j + 1];
            short8 hi8;
            hi8[0] = (short)f32_to_bf16(v0.x); ss = fmaf(v0.x, v0.x, ss);
            hi8[1] = (short)f32_to_bf16(v0.y); ss = fmaf(v0.y, v0.y, ss);
            hi8[2] = (short)f32_to_bf16(v0.z); ss = fmaf(v0.z, v0.z, ss);
            hi8[3] = (short)f32_to_bf16(v0.w); ss = fmaf(v0.w, v0.w, ss);
            hi8[4] = (short)f32_to_bf16(v1.x); ss = fmaf(v1.x, v1.x, ss);
            hi8[5] = (short)f32_to_bf16(v1.y); ss = fmaf(v1.y, v1.y, ss);
            hi8[6] = (short)f32_to_bf16(v1.z); ss = fmaf(v1.z, v1.z, ss);
            hi8[7] = (short)f32_to_bf16(v1.w); ss = fmaf(v1.w, v1.w, ss);
            *(short8*)(EH + r_ * 256 + ((h_ * 64 + j * 16) ^ swzr)) = hi8;
        }
        ss += __shfl_xor(ss, 1, 64);
        ss += __shfl_xor(ss, 2, 64);
        if (h_ == 0) E2L[r_] = ss;
        if (t < 64) { int gc = tb + t; if (gc > E - 1) gc = E - 1; EBL[t] = ent_bias[gc]; }
        if (lds_qb) {
            for (int i = t; i < B; i += 256) { Q2S[i] = q2a[i]; BSS[i] = bsa[i]; }
        }
    }
    __syncthreads();

    // column validity (per n), cheap per-block
    bool cvr[4];
    #pragma unroll
    for (int n = 0; n < 4; ++n) cvr[n] = (tb + n * 16 + l15 < E);

    #pragma unroll 1
    for (int bm = 0; bm < nbm; ++bm) {
        const int bmb = bm << 6;

        // A fragments: 16 rows per wave (4 x b128 loads, L2-hot)
        short8 AH[4];
        {
            int ar = bmb + wid * 16 + l15;
            if (ar > B - 1) ar = B - 1;
            const char* ph = (const char*)qh + (size_t)ar * 256 + lk * 16;
            #pragma unroll
            for (int kk = 0; kk < 4; ++kk)
                AH[kk] = *(const short8*)(ph + kk * 64);
        }
        // per-row scalars (rows lk*4+r)
        float q2r[4], bsr[4];
        #pragma unroll
        for (int r = 0; r < 4; ++r) {
            int row = bmb + wid * 16 + lk * 4 + r;
            int rc = row < B ? row : (B - 1);
            q2r[r] = lds_qb ? Q2S[rc] : q2a[rc];
            bsr[r] = lds_qb ? BSS[rc] : bsa[rc];
        }

        f32x4 acc[4];
        #pragma unroll
        for (int n = 0; n < 4; ++n) acc[n] = (f32x4){0.f, 0.f, 0.f, 0.f};

        __builtin_amdgcn_s_setprio(1);
        #pragma unroll
        for (int kk = 0; kk < 4; ++kk) {
            const int ko = (kk * 64 + lk * 16) ^ rswz;
            #pragma unroll
            for (int n = 0; n < 4; ++n) {
                short8 BH = *(const short8*)(EH + (n * 16 + l15) * 256 + ko);
                acc[n] = __builtin_amdgcn_mfma_f32_16x16x32_bf16(AH[kk], BH, acc[n], 0, 0, 0);
            }
        }
        __builtin_amdgcn_s_setprio(0);

        // per-n constants from LDS
        float e2q[4], beq[4];
        #pragma unroll
        for (int n = 0; n < 4; ++n) {
            e2q[n] = E2L[n * 16 + l15];
            beq[n] = EBL[n * 16 + l15];
        }

        // fused epilogue (Mobius-norm identity), rows outer / cols inner
        #pragma unroll
        for (int r = 0; r < 4; ++r) {
            const int row = bmb + wid * 16 + lk * 4 + r;
            const float q2 = q2r[r];
            const float c2q2 = c * c * q2;
            const unsigned base = (unsigned)row * (unsigned)E;
            const bool rv = (row < B);
            #pragma unroll
            for (int n = 0; n < 4; ++n) {
                const float d  = acc[n][r];
                const float e2 = e2q[n];
                float den  = fmaf(-2.f * c, d, fmaf(c2q2, e2, 1.f));
                float num  = fmaf(-2.f, d, q2 + e2);
                float inv  = __builtin_amdgcn_rcpf(den);
                float sc   = fmaf(-num, inv, beq[n] + bsr[r]);
                if (rv && cvr[n])
                    out[base + (unsigned)(tb + n * 16 + l15)] = sc;
            }
        }
    }
}

extern "C" void kernel_launch(void* const* d_in, const int* in_sizes, int n_in,
                              void* d_out, int out_size, void* d_ws, size_t ws_size,
                              hipStream_t stream) {
    const float* ent       = (const float*)d_in[0];
    // d_in[1] = rel_embedding (unused)
    const int*   trip      = (const int*)d_in[2];
    const float* rel_diag  = (const float*)d_in[3];
    const float* rel_trans = (const float*)d_in[4];
    const float* ent_bias  = (const float*)d_in[5];

    const int D = 128;
    const int E = in_sizes[0] / D;
    const int B = in_sizes[2] / 3;

    unsigned char* ws = (unsigned char*)d_ws;
    unsigned short* qh = (unsigned short*)ws;               // B*128 bf16
    float* q2w = (float*)(ws + 131072);                     // B
    float* bsw = (float*)(ws + 131072 + 2048);              // B

    build_queries<<<B, 64, 0, stream>>>(ent, trip, rel_diag, rel_trans, ent_bias,
                                        qh, q2w, bsw);

    const int ntiles = (E + 63) / 64;
    gemm_score<<<ntiles, 256, 0, stream>>>(ent, ent_bias, qh, q2w, bsw,
                                           (float*)d_out, E, B);
}